// Round 3
// baseline (337.444 us; speedup 1.0000x reference)
//
#include <hip/hip_runtime.h>

// SSIM loss, fused: separable 11x11 Gaussian blur of 5 fields + ssim + mean.
// Round 3: TH=16 tile -> 35.4 KB LDS -> 4 blocks/CU (occupancy was round 2's
// killer). Direct-global hblur (no raw LDS stage), b128 LDS writes, scalar
// conflict-free column vblur, atomic-ticket finalize, single launch.

#define TW 64
#define TH 16
#define HALO 5
#define RH (TH + 2*HALO)   // 26 hblurred rows per tile
#define HS 68              // h row stride (words): rows 16B-aligned, bank-spread
#define NBLK 8192          // 8 x 32 x 32

typedef float f4 __attribute__((ext_vector_type(4)));

__device__ __forceinline__ void hblur8_store(const float* __restrict__ W,
                                             const float (&x)[18],
                                             float* dst) {
    float s[8];
#pragma unroll
    for (int i = 0; i < 8; ++i) {
        float a = 0.f;
#pragma unroll
        for (int k = 0; k < 11; ++k) a = __builtin_fmaf(W[k], x[i + k], a);
        s[i] = a;
    }
    f4 lo, hi;
    lo.x = s[0]; lo.y = s[1]; lo.z = s[2]; lo.w = s[3];
    hi.x = s[4]; hi.y = s[5]; hi.z = s[6]; hi.w = s[7];
    *(f4*)dst = lo;
    *(f4*)(dst + 4) = hi;
}

__global__ __launch_bounds__(256, 4)
void ssim_main(const float* __restrict__ pred, const float* __restrict__ targ,
               float* __restrict__ acc, unsigned int* __restrict__ cnt,
               float* __restrict__ out) {
    const float W[11] = {
        0.00102840f, 0.00759876f, 0.03600077f, 0.10936070f, 0.21300554f,
        0.26601173f,
        0.21300554f, 0.10936070f, 0.03600077f, 0.00759876f, 0.00102840f};

    __shared__ float h[5][RH][HS];   // 35,360 B -> 4 blocks/CU
    __shared__ float wsum[4];

    const int tid = threadIdx.x;
    const int n = blockIdx.z;
    const float* __restrict__ pim = pred + (size_t)n * (512 * 512);
    const float* __restrict__ tim = targ + (size_t)n * (512 * 512);
    const int tr0 = blockIdx.y * TH - HALO;
    const int tc0 = blockIdx.x * TW - HALO;
    const bool inner = (blockIdx.x > 0) & (blockIdx.x < 7) &
                       (blockIdx.y > 0) & (blockIdx.y < 31);

    // ---- Phase A: hblur 5 fields straight from global into LDS ----
    // 26 rows x 8 col-groups (8 outputs each) = 208 tasks, <=1 per thread
    if (tid < RH * 8) {
        const int r = tid >> 3;
        const int cb8 = (tid & 7) << 3;
        const int gr = tr0 + r;
        const int gc0 = tc0 + cb8;

        float p[18], t[18];
        if (inner) {
            const float* pr = pim + gr * 512 + gc0;
            const float* tr = tim + gr * 512 + gc0;
#pragma unroll
            for (int k = 0; k < 18; ++k) { p[k] = pr[k]; t[k] = tr[k]; }
        } else {
            const bool rok = (unsigned)gr < 512u;
            const int grc = min(max(gr, 0), 511);
            const float* pr = pim + grc * 512;
            const float* tr = tim + grc * 512;
#pragma unroll
            for (int k = 0; k < 18; ++k) {
                int gc = gc0 + k;
                bool ok = rok & ((unsigned)gc < 512u);
                int gcc = min(max(gc, 0), 511);
                float pv = pr[gcc], tv = tr[gcc];
                p[k] = ok ? pv : 0.f;
                t[k] = ok ? tv : 0.f;
            }
        }

        hblur8_store(W, p, &h[0][r][cb8]);
        hblur8_store(W, t, &h[1][r][cb8]);
        float q[18];
#pragma unroll
        for (int k = 0; k < 18; ++k) q[k] = p[k] * p[k];
        hblur8_store(W, q, &h[2][r][cb8]);
#pragma unroll
        for (int k = 0; k < 18; ++k) q[k] = t[k] * t[k];
        hblur8_store(W, q, &h[3][r][cb8]);
#pragma unroll
        for (int k = 0; k < 18; ++k) q[k] = p[k] * t[k];
        hblur8_store(W, q, &h[4][r][cb8]);
    }
    __syncthreads();

    // ---- Phase C: vblur (scalar, conflict-free columns) + ssim ----
    // 64 cols x 4 row-groups (4 rows each) = 256 tasks, all threads active
    const int c = tid & 63;
    const int r0 = (tid >> 6) * 4;

    float mu[5][4];
#pragma unroll
    for (int f = 0; f < 5; ++f) {
        float win[14];
#pragma unroll
        for (int k = 0; k < 14; ++k) win[k] = h[f][r0 + k][c];
#pragma unroll
        for (int i = 0; i < 4; ++i) {
            float s = 0.f;
#pragma unroll
            for (int k = 0; k < 11; ++k)
                s = __builtin_fmaf(W[k], win[i + k], s);
            mu[f][i] = s;
        }
    }

    float lsum = 0.f;
#pragma unroll
    for (int i = 0; i < 4; ++i) {
        float m1 = mu[0][i], m2 = mu[1][i];
        float m1s = m1 * m1, m2s = m2 * m2, m12 = m1 * m2;
        float s1 = mu[2][i] - m1s;
        float s2 = mu[3][i] - m2s;
        float s12 = mu[4][i] - m12;
        float num = (2.f * m12 + 1e-4f) * (2.f * s12 + 9e-4f);
        float den = (m1s + m2s + 1e-4f) * (s1 + s2 + 9e-4f);
        float rc = __builtin_amdgcn_rcpf(den);
        rc = rc * (2.f - den * rc);  // one Newton step
        lsum = __builtin_fmaf(num, rc, lsum);
    }

    // ---- Reduce: wave shuffle -> block -> one atomic; ticket finalize ----
#pragma unroll
    for (int off = 32; off > 0; off >>= 1)
        lsum += __shfl_down(lsum, off, 64);
    if ((tid & 63) == 0) wsum[tid >> 6] = lsum;
    __syncthreads();
    if (tid == 0) {
        float b = wsum[0] + wsum[1] + wsum[2] + wsum[3];
        atomicAdd(acc, b);
        __threadfence();
        unsigned int old = atomicAdd(cnt, 1u);
        if (old == NBLK - 1) {
            float s = atomicAdd(acc, 0.f);   // coherent read of final sum
            out[0] = 1.0f - s * (1.0f / 8388608.0f);
        }
    }
}

extern "C" void kernel_launch(void* const* d_in, const int* in_sizes, int n_in,
                              void* d_out, int out_size, void* d_ws,
                              size_t ws_size, hipStream_t stream) {
    const float* pred = (const float*)d_in[0];
    const float* targ = (const float*)d_in[1];
    float* acc = (float*)d_ws;
    unsigned int* cnt = (unsigned int*)((char*)d_ws + 4);

    hipMemsetAsync(d_ws, 0, 8, stream);
    dim3 grid(512 / TW, 512 / TH, 32);  // 8 x 32 x 32 = 8192 blocks
    ssim_main<<<grid, dim3(256), 0, stream>>>(pred, targ, acc, cnt,
                                              (float*)d_out);
    (void)in_sizes; (void)n_in; (void)out_size; (void)ws_size;
}

// Round 4
// 201.231 us; speedup vs baseline: 1.6769x; 1.6769x over previous
//
#include <hip/hip_runtime.h>

// SSIM loss, round 4: barrier-free register-ring kernel.
// One wave owns a 54-col x 64-row output strip. Slide down rows:
//   load raw p,t (coalesced) -> __shfl 11-wide horizontal window ->
//   hblur 5 fields in regs -> register ring h[5][11] (compile-time indexed)
//   -> vblur + ssim -> wave-reduce -> 1 atomic/wave -> ticket finalize.
// No __syncthreads, no LDS tiles, peak live regs ~110.

#define SW 54                       // output cols per wave (lanes 54..63 halo)
#define NSTRIP 10                   // ceil(512/54); last strip partial
#define H 64                        // output rows per band
#define NBAND 8                     // 512/64
#define NIMG 32
#define NTASK (NSTRIP * NBAND * NIMG)   // 2560 one-wave blocks

__global__ __launch_bounds__(64, 4)
void ssim_main(const float* __restrict__ pred, const float* __restrict__ targ,
               float* __restrict__ acc, unsigned int* __restrict__ cnt,
               float* __restrict__ out) {
    const float W[11] = {
        0.00102840f, 0.00759876f, 0.03600077f, 0.10936070f, 0.21300554f,
        0.26601173f,
        0.21300554f, 0.10936070f, 0.03600077f, 0.00759876f, 0.00102840f};

    const int task  = blockIdx.x;
    const int img   = task / (NSTRIP * NBAND);
    const int rem   = task - img * (NSTRIP * NBAND);
    const int band  = rem / NSTRIP;
    const int strip = rem - band * NSTRIP;

    const int L = threadIdx.x;                 // lane 0..63
    const int craw = strip * SW - 5 + L;       // raw col this lane loads
    const bool colOK = (unsigned)craw < 512u;
    const int cidx = min(max(craw, 0), 511);
    const int co = strip * SW + L;             // output col (lanes 0..53)
    const bool outCol = (L < SW) & (co < 512);

    const float* __restrict__ pim = pred + (size_t)img * 262144 + cidx;
    const float* __restrict__ tim = targ + (size_t)img * 262144 + cidx;
    const int rb = band * H;

    float ring[5][11];                         // hblurred rows, reg-resident
    float lsum = 0.f;

    // raw rows rb-5 .. rb+68 -> 74 steps; outer stride 11 keeps ring indices
    // compile-time (slot == ph since ibase % 11 == 0).
    for (int ibase = 0; ibase < 77; ibase += 11) {
#pragma unroll
        for (int ph = 0; ph < 11; ++ph) {
            const int i = ibase + ph;
            if (i < 74) {
                const int rr = rb - 5 + i;
                float p = 0.f, t = 0.f;
                if ((unsigned)rr < 512u) {     // wave-uniform branch
                    const float pv = pim[rr << 9];
                    const float tv = tim[rr << 9];
                    p = colOK ? pv : 0.f;      // zero-pad conv semantics
                    t = colOK ? tv : 0.f;
                }

                // horizontal 11-window via cross-lane shuffle (raw p,t only)
                float pw[11], tw[11];
                pw[0] = p; tw[0] = t;
#pragma unroll
                for (int d = 1; d <= 10; ++d) {
                    pw[d] = __shfl(p, L + d, 64);
                    tw[d] = __shfl(t, L + d, 64);
                }

                // hblur of 5 fields (products formed from shuffled window)
                float hp = 0.f, ht = 0.f, hpp = 0.f, htt = 0.f, hpt = 0.f;
#pragma unroll
                for (int k = 0; k < 11; ++k) {
                    const float a = pw[k], b = tw[k], w = W[k];
                    hp  = __builtin_fmaf(w, a, hp);
                    ht  = __builtin_fmaf(w, b, ht);
                    hpp = __builtin_fmaf(w, a * a, hpp);
                    htt = __builtin_fmaf(w, b * b, htt);
                    hpt = __builtin_fmaf(w, a * b, hpt);
                }
                ring[0][ph] = hp;  ring[1][ph] = ht;  ring[2][ph] = hpp;
                ring[3][ph] = htt; ring[4][ph] = hpt;

                // vblur + ssim once the ring is full (output row rr-5)
                if (i >= 10) {
                    float mu[5];
#pragma unroll
                    for (int f = 0; f < 5; ++f) {
                        float s = 0.f;
#pragma unroll
                        for (int k = 0; k < 11; ++k)
                            s = __builtin_fmaf(W[k], ring[f][(ph + 1 + k) % 11], s);
                        mu[f] = s;
                    }
                    const float m1 = mu[0], m2 = mu[1];
                    const float m1s = m1 * m1, m2s = m2 * m2, m12 = m1 * m2;
                    const float s1 = mu[2] - m1s;
                    const float s2 = mu[3] - m2s;
                    const float s12 = mu[4] - m12;
                    const float num = (2.f * m12 + 1e-4f) * (2.f * s12 + 9e-4f);
                    const float den = (m1s + m2s + 1e-4f) * (s1 + s2 + 9e-4f);
                    float rc = __builtin_amdgcn_rcpf(den);
                    rc = rc * (2.f - den * rc);          // one Newton step
                    lsum += outCol ? num * rc : 0.f;     // mask halo lanes
                }
            }
        }
    }

    // wave reduce -> one atomic per wave; last wave finalizes
#pragma unroll
    for (int off = 32; off > 0; off >>= 1)
        lsum += __shfl_down(lsum, off, 64);
    if (L == 0) {
        atomicAdd(acc, lsum);
        __threadfence();
        if (atomicAdd(cnt, 1u) == NTASK - 1) {
            const float s = atomicAdd(acc, 0.f);   // coherent final read
            out[0] = 1.0f - s * (1.0f / 8388608.0f);
        }
    }
}

extern "C" void kernel_launch(void* const* d_in, const int* in_sizes, int n_in,
                              void* d_out, int out_size, void* d_ws,
                              size_t ws_size, hipStream_t stream) {
    const float* pred = (const float*)d_in[0];
    const float* targ = (const float*)d_in[1];
    float* acc = (float*)d_ws;
    unsigned int* cnt = (unsigned int*)((char*)d_ws + 4);

    hipMemsetAsync(d_ws, 0, 8, stream);
    ssim_main<<<dim3(NTASK), dim3(64), 0, stream>>>(pred, targ, acc, cnt,
                                                    (float*)d_out);
    (void)in_sizes; (void)n_in; (void)out_size; (void)ws_size;
}